// Round 5
// baseline (426.160 us; speedup 1.0000x reference)
//
#include <hip/hip_runtime.h>
#include <hip/hip_bf16.h>
#include <stdint.h>

#define BATCH 8
#define SEQ   4096
#define EMB   1024
#define HD    128
#define NROWS 32768

typedef __attribute__((ext_vector_type(8))) short short8;
typedef __attribute__((ext_vector_type(4))) float f32x4;

__device__ inline unsigned short f2bf(float f) {
    union { float f; unsigned int u; } c; c.f = f;
    unsigned int u = c.u;
    unsigned int r = (u + 0x7fffu + ((u >> 16) & 1u)) >> 16;
    return (unsigned short)r;
}
__device__ inline float bf2f(unsigned short u) {
    union { unsigned int i; float f; } c; c.i = ((unsigned int)u) << 16; return c.f;
}
__device__ inline unsigned int pkbf(float a, float b) {
    __hip_bfloat162 h = __float22bfloat162_rn(make_float2(a, b));
    union { __hip_bfloat162 h; unsigned int u; } c; c.h = h; return c.u;
}

#define GLDS16(gp, lp) __builtin_amdgcn_global_load_lds( \
    (const __attribute__((address_space(1))) void*)(gp), \
    (__attribute__((address_space(3))) void*)(lp), 16, 0, 0)

// ---------------------------------------------------------------------------
// prep: wt[n][k] = bf16(W[k][h]) for n = sel*128+h. 384 blocks, one row each.
// ---------------------------------------------------------------------------
__global__ __launch_bounds__(256) void prep_kernel(
    const float* __restrict__ Wq, const float* __restrict__ bq,
    const float* __restrict__ Wk, const float* __restrict__ bk,
    const float* __restrict__ Wv, const float* __restrict__ bv,
    unsigned short* __restrict__ wt, float* __restrict__ biasc)
{
    const int n = blockIdx.x;           // 0..383
    const int sel = n >> 7, h = n & 127;
    const float* W = (sel == 0) ? Wq : (sel == 1) ? Wk : Wv;
    const int tid = threadIdx.x;
    const int k0 = tid * 4;
    union { unsigned short us[4]; uint2 v; } pk;
#pragma unroll
    for (int u = 0; u < 4; ++u) pk.us[u] = f2bf(W[(size_t)(k0 + u) * HD + h]);
    *(uint2*)&wt[(size_t)n * EMB + k0] = pk.v;
    if (tid == 0) {
        const float* bp = (sel == 0) ? bq : (sel == 1) ? bk : bv;
        biasc[n] = bp[h];
    }
}

// ---------------------------------------------------------------------------
// gemm_qkv: fused QKV. 512 blocks x 64 rows x 384 cols; 8 waves, wave tile
// 48 cols x 64 rows. Write-behind pipeline: ds_write at iter kt stores x
// loaded at kt-1 (resident after barrier drain -> no mid-iter vmcnt stall).
// As triple-buffered, Bs double-buffered. Exact 2-way swizzle on all b128
// LDS reads: chunk' = chunk ^ ((row>>1)&3).
// ---------------------------------------------------------------------------
__global__ __launch_bounds__(512, 4) void gemm_qkv(
    const float* __restrict__ x, const unsigned short* __restrict__ wt,
    const float* __restrict__ biasc,
    unsigned short* __restrict__ q, unsigned short* __restrict__ kOut,
    unsigned short* __restrict__ vt)
{
    const int m0  = blockIdx.x * 64;
    const int tid = threadIdx.x;
    const int wave = tid >> 6, lane = tid & 63;
    const int quad = lane >> 4, l15 = lane & 15;

    __shared__ __align__(16) unsigned short As[3][2048];     // 3 x 64 rows x 32 k (swizzled)
    __shared__ __align__(16) unsigned short Bs[2][12288];    // 2 x 384 n x 32 k (swizzled)

    f32x4 acc[3][4];
#pragma unroll
    for (int i = 0; i < 3; ++i)
#pragma unroll
        for (int j = 0; j < 4; ++j) acc[i][j] = (f32x4){0.f, 0.f, 0.f, 0.f};

    const int arow = tid >> 3, akc = (tid & 7) * 4;
    const int awidx = arow * 32 + ((((akc >> 3) ^ ((arow >> 1) & 3))) << 3) + (akc & 7);
    float4 aR[2];

#define LOAD_A(kt, slot) aR[slot] = *(const float4*)(x + (size_t)(m0 + arow) * EMB + (kt) * 32 + akc);
#define WRITE_A(buf, slot)                                                  \
    {                                                                       \
        union { unsigned short us[4]; uint2 v; } pw;                        \
        pw.us[0] = f2bf(aR[slot].x); pw.us[1] = f2bf(aR[slot].y);           \
        pw.us[2] = f2bf(aR[slot].z); pw.us[3] = f2bf(aR[slot].w);           \
        *(uint2*)&As[buf][awidx] = pw.v;                                    \
    }
#define STAGE_B(kt, buf)                                                    \
    {                                                                       \
        _Pragma("unroll")                                                   \
        for (int g = 0; g < 3; ++g) {                                       \
            int s0 = (g * 8 + wave) * 64;                                   \
            int s  = s0 + lane;                                             \
            int n  = s >> 2, csw = s & 3;                                   \
            int c  = csw ^ ((n >> 1) & 3);                                  \
            GLDS16(wt + (size_t)n * EMB + (kt) * 32 + c * 8,                \
                   &Bs[buf][s0 * 8]);                                       \
        }                                                                   \
    }

    LOAD_A(0, 0); LOAD_A(1, 1);
    STAGE_B(0, 0); STAGE_B(1, 1);
    WRITE_A(0, 0);          // waits on x(0) only
    LOAD_A(2, 0);

    int cur3 = 0;
    for (int kt = 0; kt < 32; ++kt) {
        __syncthreads();
        if (kt >= 1 && kt < 31) STAGE_B(kt + 1, (kt + 1) & 1);
        short8 af[4], bw[3];
#pragma unroll
        for (int mj = 0; mj < 4; ++mj) {
            int row = mj * 16 + l15;
            af[mj] = *(const short8*)&As[cur3][row * 32 + ((quad ^ ((row >> 1) & 3)) << 3)];
        }
#pragma unroll
        for (int ni = 0; ni < 3; ++ni) {
            int n = wave * 48 + ni * 16 + l15;
            bw[ni] = *(const short8*)&Bs[kt & 1][n * 32 + ((quad ^ ((n >> 1) & 3)) << 3)];
        }
#pragma unroll
        for (int ni = 0; ni < 3; ++ni)
#pragma unroll
            for (int mj = 0; mj < 4; ++mj)
                acc[ni][mj] = __builtin_amdgcn_mfma_f32_16x16x32_bf16(
                    bw[ni], af[mj], acc[ni][mj], 0, 0, 0);
        if (kt < 31) {
            int nxt3 = (cur3 == 2) ? 0 : cur3 + 1;
            WRITE_A(nxt3, (kt + 1) & 1);       // data loaded at kt-1, already resident
            cur3 = nxt3;
        }
        if (kt < 30) LOAD_A(kt + 2, kt & 1);
    }

    const float qscale = 0.08838834764831845f * 1.4426950408889634f; // 1/sqrt(128)*log2e
    const int bb = m0 >> 12;
    const int t0 = m0 & 4095;
#pragma unroll
    for (int ni = 0; ni < 3; ++ni) {
        int colbase = wave * 48 + ni * 16;
        int sel = colbase >> 7;
        int c0 = colbase + quad * 4;
        float4 bv4 = *(const float4*)&biasc[c0];
#pragma unroll
        for (int mj = 0; mj < 4; ++mj) {
            int m = m0 + mj * 16 + l15;
            if (sel == 0) {
                union { unsigned short us[4]; uint2 v; } pk;
#pragma unroll
                for (int j = 0; j < 4; ++j)
                    pk.us[j] = f2bf((acc[ni][mj][j] + ((const float*)&bv4)[j]) * qscale);
                *(uint2*)&q[(size_t)m * HD + (c0 & 127)] = pk.v;
            } else if (sel == 1) {
                union { unsigned short us[4]; uint2 v; } pk;
#pragma unroll
                for (int j = 0; j < 4; ++j)
                    pk.us[j] = f2bf(acc[ni][mj][j] + ((const float*)&bv4)[j]);
                *(uint2*)&kOut[(size_t)m * HD + (c0 & 127)] = pk.v;
            } else {
#pragma unroll
                for (int j = 0; j < 4; ++j) {
                    int h = (c0 & 127) + j;
                    vt[((size_t)(bb * 128 + h)) * SEQ + t0 + mj * 16 + l15] =
                        f2bf(acc[ni][mj][j] + ((const float*)&bv4)[j]);
                }
            }
        }
    }
#undef LOAD_A
#undef WRITE_A
#undef STAGE_B
}

// ---------------------------------------------------------------------------
// attn: flash attention, S^T formulation, ZERO LDS / ZERO barriers.
// 512 blocks (32 qt x 2 parity x 8 batch, LPT order) x 4 waves; wave owns
// 32 q-rows, K/V fragments loaded directly from global (L2/L3-resident).
// Waves retire independently (per-wave causal break). Split-K halves merged
// by merge_kernel.
// ---------------------------------------------------------------------------
__global__ __launch_bounds__(256, 2) void attn_kernel(
    const unsigned short* __restrict__ q, const unsigned short* __restrict__ k,
    const unsigned short* __restrict__ vt, float* __restrict__ outA,
    unsigned short* __restrict__ Oh, float2* __restrict__ ml)
{
    const int rank   = blockIdx.x;            // 0..511
    const int qt     = 31 - (rank >> 4);      // heavy tiles first (LPT)
    const int parity = (rank >> 3) & 1;
    const int b      = rank & 7;
    const int tid  = threadIdx.x;
    const int wave = tid >> 6, lane = tid & 63;
    const int quad = lane >> 4, l15 = lane & 15;
    const int qrow0 = qt * 128 + wave * 32;
    const size_t qbase = (size_t)b * SEQ;
    const size_t vbase = (size_t)b * HD * SEQ;

    // Q resident as B-operand frags
    short8 qf[2][4];
#pragma unroll
    for (int mi = 0; mi < 2; ++mi)
#pragma unroll
        for (int kh = 0; kh < 4; ++kh)
            qf[mi][kh] = *(const short8*)(q + (qbase + qrow0 + mi * 16 + l15) * HD + kh * 32 + quad * 8);

    f32x4 o[2][8];
#pragma unroll
    for (int mi = 0; mi < 2; ++mi)
#pragma unroll
        for (int hi = 0; hi < 8; ++hi) o[mi][hi] = (f32x4){0.f, 0.f, 0.f, 0.f};
    float m_r[2] = {-1e30f, -1e30f};
    float l_r[2] = {0.f, 0.f};

    const int bpa0 = (l15 + 16 * ((2 * quad) & 3)) * 4;       // bpermute byte addrs
    const int bpa1 = (l15 + 16 * ((2 * quad + 1) & 3)) * 4;

    const int niter = qt + 1;
    for (int i = 0; i < niter; ++i) {
        const int kt = parity + 2 * i;
        const int key0 = kt * 64;
        if (key0 > qrow0 + 31) break;          // strictly-future keys: done

        // ---- load K frags (16B/lane, L2-hot), then S^T = K Q^T ----
        short8 kf[4][4];
#pragma unroll
        for (int kh = 0; kh < 4; ++kh)
#pragma unroll
            for (int ni = 0; ni < 4; ++ni)
                kf[kh][ni] = *(const short8*)(k + (qbase + key0 + ni * 16 + l15) * HD + kh * 32 + quad * 8);

        f32x4 s[2][4];
#pragma unroll
        for (int mi = 0; mi < 2; ++mi)
#pragma unroll
            for (int ni = 0; ni < 4; ++ni) s[mi][ni] = (f32x4){0.f, 0.f, 0.f, 0.f};
#pragma unroll
        for (int kh = 0; kh < 4; ++kh)
#pragma unroll
            for (int ni = 0; ni < 4; ++ni) {
                s[0][ni] = __builtin_amdgcn_mfma_f32_16x16x32_bf16(kf[kh][ni], qf[0][kh], s[0][ni], 0, 0, 0);
                s[1][ni] = __builtin_amdgcn_mfma_f32_16x16x32_bf16(kf[kh][ni], qf[1][kh], s[1][ni], 0, 0, 0);
            }
        // ---- causal mask ----
        if (key0 + 63 > qrow0) {
#pragma unroll
            for (int mi = 0; mi < 2; ++mi)
#pragma unroll
                for (int ni = 0; ni < 4; ++ni)
#pragma unroll
                    for (int j = 0; j < 4; ++j) {
                        int key = key0 + ni * 16 + quad * 4 + j;
                        int t   = qrow0 + mi * 16 + l15;
                        if (key > t) s[mi][ni][j] = -1e30f;
                    }
        }
        // ---- online softmax (per-lane scalar) + P pack ----
        unsigned int pk[2][4][2];
#pragma unroll
        for (int mi = 0; mi < 2; ++mi) {
            float mx = -1e30f;
#pragma unroll
            for (int ni = 0; ni < 4; ++ni)
#pragma unroll
                for (int j = 0; j < 4; ++j) mx = fmaxf(mx, s[mi][ni][j]);
            mx = fmaxf(mx, __shfl_xor(mx, 16));
            mx = fmaxf(mx, __shfl_xor(mx, 32));
            float mnew = fmaxf(m_r[mi], mx);
            float alpha = __builtin_amdgcn_exp2f(m_r[mi] - mnew);
            m_r[mi] = mnew;
            float rs = 0.f;
#pragma unroll
            for (int ni = 0; ni < 4; ++ni) {
                float p0 = __builtin_amdgcn_exp2f(s[mi][ni][0] - mnew);
                float p1 = __builtin_amdgcn_exp2f(s[mi][ni][1] - mnew);
                float p2 = __builtin_amdgcn_exp2f(s[mi][ni][2] - mnew);
                float p3 = __builtin_amdgcn_exp2f(s[mi][ni][3] - mnew);
                rs += (p0 + p1) + (p2 + p3);
                pk[mi][ni][0] = pkbf(p0, p1);
                pk[mi][ni][1] = pkbf(p2, p3);
            }
            rs += __shfl_xor(rs, 16);
            rs += __shfl_xor(rs, 32);
            l_r[mi] = alpha * l_r[mi] + rs;
#pragma unroll
            for (int hi = 0; hi < 8; ++hi) o[mi][hi] *= alpha;
        }
        // ---- P^T B-frags via cross-quad bpermute ----
        short8 pT[2][2];
#pragma unroll
        for (int mi = 0; mi < 2; ++mi)
#pragma unroll
            for (int sk = 0; sk < 2; ++sk) {
                union { unsigned int u[4]; short8 s8; } pt;
                int lo = 2 * sk, hi_ = 2 * sk + 1;
                unsigned int a0 = (unsigned)__builtin_amdgcn_ds_bpermute(bpa0, (int)pk[mi][lo][0]);
                unsigned int b0 = (unsigned)__builtin_amdgcn_ds_bpermute(bpa0, (int)pk[mi][hi_][0]);
                pt.u[0] = (quad < 2) ? a0 : b0;
                unsigned int a1 = (unsigned)__builtin_amdgcn_ds_bpermute(bpa0, (int)pk[mi][lo][1]);
                unsigned int b1 = (unsigned)__builtin_amdgcn_ds_bpermute(bpa0, (int)pk[mi][hi_][1]);
                pt.u[1] = (quad < 2) ? a1 : b1;
                unsigned int a2 = (unsigned)__builtin_amdgcn_ds_bpermute(bpa1, (int)pk[mi][lo][0]);
                unsigned int b2 = (unsigned)__builtin_amdgcn_ds_bpermute(bpa1, (int)pk[mi][hi_][0]);
                pt.u[2] = (quad < 2) ? a2 : b2;
                unsigned int a3 = (unsigned)__builtin_amdgcn_ds_bpermute(bpa1, (int)pk[mi][lo][1]);
                unsigned int b3 = (unsigned)__builtin_amdgcn_ds_bpermute(bpa1, (int)pk[mi][hi_][1]);
                pt.u[3] = (quad < 2) ? a3 : b3;
                pT[mi][sk] = pt.s8;
            }
        // ---- O^T += V^T P^T (V frags direct from global) ----
        short8 vf[2][8];
#pragma unroll
        for (int sk = 0; sk < 2; ++sk)
#pragma unroll
            for (int hi = 0; hi < 8; ++hi)
                vf[sk][hi] = *(const short8*)(vt + vbase + (size_t)(hi * 16 + l15) * SEQ + key0 + sk * 32 + quad * 8);
#pragma unroll
        for (int sk = 0; sk < 2; ++sk)
#pragma unroll
            for (int hi = 0; hi < 8; ++hi) {
                o[0][hi] = __builtin_amdgcn_mfma_f32_16x16x32_bf16(vf[sk][hi], pT[0][sk], o[0][hi], 0, 0, 0);
                o[1][hi] = __builtin_amdgcn_mfma_f32_16x16x32_bf16(vf[sk][hi], pT[1][sk], o[1][hi], 0, 0, 0);
            }
    }

    // ---- epilogue: unnormalized halves + (m,l) ----
#pragma unroll
    for (int mi = 0; mi < 2; ++mi) {
        size_t rowg = qbase + qrow0 + mi * 16 + l15;
        if (quad == 0) ml[(size_t)parity * NROWS + rowg] = make_float2(m_r[mi], l_r[mi]);
#pragma unroll
        for (int hi = 0; hi < 8; ++hi) {
            if (parity == 0) {
                *(f32x4*)&outA[rowg * HD + hi * 16 + quad * 4] = o[mi][hi];
            } else {
                union { unsigned short us[4]; uint2 v; } pw;
#pragma unroll
                for (int j = 0; j < 4; ++j) pw.us[j] = f2bf(o[mi][hi][j]);
                *(uint2*)&Oh[rowg * HD + hi * 16 + quad * 4] = pw.v;
            }
        }
    }
}

// ---------------------------------------------------------------------------
// merge: out = (w0*O0 + w1*O1) / (w0*l0 + w1*l1), w = exp2(m - max(m0,m1)).
// ---------------------------------------------------------------------------
__global__ __launch_bounds__(256) void merge_kernel(
    float* __restrict__ out, const unsigned short* __restrict__ Oh,
    const float2* __restrict__ ml)
{
    int idx = blockIdx.x * 256 + threadIdx.x;   // < NROWS*32
    int row = idx >> 5;
    int hc  = (idx & 31) << 2;
    float2 a = ml[row];
    float2 c = ml[NROWS + row];
    float M  = fmaxf(a.x, c.x);
    float w0 = __builtin_amdgcn_exp2f(a.x - M);
    float w1 = __builtin_amdgcn_exp2f(c.x - M);
    float inv = 1.0f / (w0 * a.y + w1 * c.y);
    f32x4 o0 = *(const f32x4*)&out[(size_t)row * HD + hc];
    union { unsigned short us[4]; uint2 v; } pv;
    pv.v = *(const uint2*)&Oh[(size_t)row * HD + hc];
    f32x4 r;
#pragma unroll
    for (int j = 0; j < 4; ++j)
        r[j] = (w0 * o0[j] + w1 * bf2f(pv.us[j])) * inv;
    *(f32x4*)&out[(size_t)row * HD + hc] = r;
}

// ---------------------------------------------------------------------------
extern "C" void kernel_launch(void* const* d_in, const int* in_sizes, int n_in,
                              void* d_out, int out_size, void* d_ws, size_t ws_size,
                              hipStream_t stream) {
    const float* x  = (const float*)d_in[0];
    const float* Wq = (const float*)d_in[1];
    const float* bq = (const float*)d_in[2];
    const float* Wk = (const float*)d_in[3];
    const float* bk = (const float*)d_in[4];
    const float* Wv = (const float*)d_in[5];
    const float* bv = (const float*)d_in[6];
    float* out = (float*)d_out;

    // ws: wt 768K | biasc 1.5K | qb 8.4M | kb 8.4M | vtb 8.4M | Oh 8.4M | ml 512K
    unsigned short* wt    = (unsigned short*)d_ws;
    float*          biasc = (float*)((char*)d_ws + 786432);
    unsigned short* qb    = (unsigned short*)((char*)d_ws + 787968);
    unsigned short* kb    = qb  + (size_t)NROWS * HD;
    unsigned short* vtb   = kb  + (size_t)NROWS * HD;
    unsigned short* Oh    = vtb + (size_t)NROWS * HD;
    float2*         ml    = (float2*)((char*)d_ws + 787968 + 4ull * NROWS * HD * 2);

    prep_kernel<<<dim3(384), 256, 0, stream>>>(Wq, bq, Wk, bk, Wv, bv, wt, biasc);
    gemm_qkv<<<dim3(512), 512, 0, stream>>>(x, wt, biasc, qb, kb, vtb);
    attn_kernel<<<dim3(512), 256, 0, stream>>>(qb, kb, vtb, out, Oh, ml);
    merge_kernel<<<dim3(NROWS * 32 / 256), 256, 0, stream>>>(out, Oh, ml);
}